// Round 1
// baseline (163.158 us; speedup 1.0000x reference)
//
#include <hip/hip_runtime.h>

// Segmented (per-ray) weighted RGB sum. ray_indices is SORTED, avg run
// length = 64 samples/ray. Each thread owns a contiguous chunk of CHUNK
// samples, accumulates runs locally, atomicAdds only at run boundaries.

#define CHUNK 16

__global__ __launch_bounds__(256) void integrate_kernel(
    const float* __restrict__ rgb,      // [n, 3]
    const float* __restrict__ w,        // [n, 1]
    const int*   __restrict__ idx,      // [n] sorted
    float*       __restrict__ out,      // [n_rays, 3], pre-zeroed
    int n)
{
    long long t    = (long long)blockIdx.x * blockDim.x + threadIdx.x;
    long long base = t * CHUNK;
    if (base >= n) return;

    if (base + CHUNK <= n) {
        // Fast path: fully vectorized chunk.
        const int4*   idx4 = (const int4*)  (idx + base);
        const float4* w4   = (const float4*)(w   + base);
        const float4* rgb4 = (const float4*)(rgb + base * 3);

        int   cur = idx[base];
        float ax = 0.f, ay = 0.f, az = 0.f;

        #pragma unroll
        for (int g = 0; g < CHUNK / 4; ++g) {
            int4   id = idx4[g];
            float4 wv = w4[g];
            float4 r0 = rgb4[3 * g + 0];
            float4 r1 = rgb4[3 * g + 1];
            float4 r2 = rgb4[3 * g + 2];

            // De-swizzle float4-of-float3: sample k -> (sx,sy,sz)
            float sx[4] = {r0.x, r0.w, r1.z, r2.y};
            float sy[4] = {r0.y, r1.x, r1.w, r2.z};
            float sz[4] = {r0.z, r1.y, r2.x, r2.w};
            int   ids[4] = {id.x, id.y, id.z, id.w};
            float ws[4]  = {wv.x, wv.y, wv.z, wv.w};

            #pragma unroll
            for (int k = 0; k < 4; ++k) {
                if (ids[k] != cur) {
                    atomicAdd(&out[cur * 3 + 0], ax);
                    atomicAdd(&out[cur * 3 + 1], ay);
                    atomicAdd(&out[cur * 3 + 2], az);
                    ax = ay = az = 0.f;
                    cur = ids[k];
                }
                ax = fmaf(ws[k], sx[k], ax);
                ay = fmaf(ws[k], sy[k], ay);
                az = fmaf(ws[k], sz[k], az);
            }
        }
        atomicAdd(&out[cur * 3 + 0], ax);
        atomicAdd(&out[cur * 3 + 1], ay);
        atomicAdd(&out[cur * 3 + 2], az);
    } else {
        // Scalar tail (not hit for n % CHUNK == 0, kept for safety).
        int   cur = idx[base];
        float ax = 0.f, ay = 0.f, az = 0.f;
        for (long long i = base; i < n; ++i) {
            int id = idx[i];
            if (id != cur) {
                atomicAdd(&out[cur * 3 + 0], ax);
                atomicAdd(&out[cur * 3 + 1], ay);
                atomicAdd(&out[cur * 3 + 2], az);
                ax = ay = az = 0.f;
                cur = id;
            }
            float wi = w[i];
            ax = fmaf(wi, rgb[i * 3 + 0], ax);
            ay = fmaf(wi, rgb[i * 3 + 1], ay);
            az = fmaf(wi, rgb[i * 3 + 2], az);
        }
        atomicAdd(&out[cur * 3 + 0], ax);
        atomicAdd(&out[cur * 3 + 1], ay);
        atomicAdd(&out[cur * 3 + 2], az);
    }
}

extern "C" void kernel_launch(void* const* d_in, const int* in_sizes, int n_in,
                              void* d_out, int out_size, void* d_ws, size_t ws_size,
                              hipStream_t stream) {
    const float* rgb = (const float*)d_in[0];   // [n,3] f32
    const float* w   = (const float*)d_in[1];   // [n,1] f32
    const int*   idx = (const int*)  d_in[2];   // [n]   i32 sorted
    float*       out = (float*)d_out;           // [n_rays,3] f32

    int n = in_sizes[2];  // sample count

    // Output is re-poisoned to 0xAA before every timed launch — zero it.
    hipMemsetAsync(d_out, 0, (size_t)out_size * sizeof(float), stream);

    long long threads = (n + CHUNK - 1) / CHUNK;
    int blocks = (int)((threads + 255) / 256);
    integrate_kernel<<<blocks, 256, 0, stream>>>(rgb, w, idx, out, n);
}

// Round 2
// 110.642 us; speedup vs baseline: 1.4747x; 1.4747x over previous
//
#include <hip/hip_runtime.h>

// Segmented (per-ray) weighted RGB sum over SORTED ray_indices.
// Strategy: coalesced loads (lane i -> sample base + u*64 + i), V windows
// preloaded per wave for MLP, then per-window wave-level segmented suffix
// scan (shuffles) so only segment-head lanes issue atomicAdds (~2 heads
// per 64-sample window at avg run length 64).

#define V 8  // 64-sample windows per wave

__global__ __launch_bounds__(256) void integrate_kernel(
    const float* __restrict__ rgb,      // [n, 3]
    const float* __restrict__ w,        // [n, 1]
    const int*   __restrict__ idx,      // [n] sorted
    float*       __restrict__ out,      // [n_rays, 3], pre-zeroed
    int n)
{
    const int lane = threadIdx.x & 63;
    const long long wave = ((long long)blockIdx.x * blockDim.x + threadIdx.x) >> 6;
    const long long base = wave * (64LL * V);
    if (base >= n) return;

    // ---- Load phase: issue everything up front (high MLP) ----
    int   ids[V];
    float vx[V], vy[V], vz[V];   // weighted rgb per window
    #pragma unroll
    for (int u = 0; u < V; ++u) {
        long long s  = base + (long long)u * 64 + lane;
        bool      ok = (s < n);
        long long sc = ok ? s : (n - 1);           // clamp; contribute 0
        int   id = idx[sc];
        float wv = ok ? w[sc] : 0.0f;
        float r  = rgb[3 * sc + 0];
        float g  = rgb[3 * sc + 1];
        float b  = rgb[3 * sc + 2];
        ids[u] = id;
        vx[u] = wv * r;
        vy[u] = wv * g;
        vz[u] = wv * b;
    }

    // ---- Reduce phase: segmented suffix scan per 64-sample window ----
    #pragma unroll
    for (int u = 0; u < V; ++u) {
        int   id = ids[u];
        float ax = vx[u], ay = vy[u], az = vz[u];

        int  prev = __shfl_up(id, 1);
        bool head = (lane == 0) || (prev != id);
        unsigned long long hm = __ballot(head);

        #pragma unroll
        for (int d = 1; d < 64; d <<= 1) {
            float ox = __shfl_down(ax, d);
            float oy = __shfl_down(ay, d);
            float oz = __shfl_down(az, d);
            // lane+d is in the same segment iff no head in (lane, lane+d]
            unsigned long long between =
                (hm >> (lane + 1)) & ((1ull << d) - 1ull);
            bool cont = (lane + d < 64) && (between == 0);
            if (cont) { ax += ox; ay += oy; az += oz; }
        }

        if (head) {
            atomicAdd(&out[id * 3 + 0], ax);
            atomicAdd(&out[id * 3 + 1], ay);
            atomicAdd(&out[id * 3 + 2], az);
        }
    }
}

extern "C" void kernel_launch(void* const* d_in, const int* in_sizes, int n_in,
                              void* d_out, int out_size, void* d_ws, size_t ws_size,
                              hipStream_t stream) {
    const float* rgb = (const float*)d_in[0];   // [n,3] f32
    const float* w   = (const float*)d_in[1];   // [n,1] f32
    const int*   idx = (const int*)  d_in[2];   // [n]   i32 sorted
    float*       out = (float*)d_out;           // [n_rays,3] f32

    int n = in_sizes[2];  // sample count

    // Output is re-poisoned to 0xAA before every timed launch — zero it.
    hipMemsetAsync(d_out, 0, (size_t)out_size * sizeof(float), stream);

    long long waves  = ((long long)n + 64LL * V - 1) / (64LL * V);
    long long blocks = (waves + 3) / 4;          // 4 waves (256 threads) per block
    integrate_kernel<<<(int)blocks, 256, 0, stream>>>(rgb, w, idx, out, n);
}